// Round 11
// baseline (7595.014 us; speedup 1.0000x reference)
//
#include <hip/hip_runtime.h>

#define Tn 1024
#define Bn 64
#define In_ 64
#define Hn 512
#define On 64
#define DTC 0.5f

typedef __attribute__((ext_vector_type(8))) short short8;   // bf16x8 MFMA frag
typedef __attribute__((ext_vector_type(4))) short short4v;  // bf16x4 (8B)
typedef __attribute__((ext_vector_type(4))) float floatx4;  // MFMA C frag
typedef unsigned long long u64;

__device__ __forceinline__ float bf2f(unsigned short u){
  union{unsigned int i; float f;} v; v.i = ((unsigned int)u)<<16; return v.f;
}
__device__ __forceinline__ unsigned short f2bf(float f){   // RNE
  union{float f; unsigned int i;} v; v.f=f;
  unsigned int x=v.i;
  return (unsigned short)((x + 0x7fffu + ((x>>16)&1u))>>16);
}
__device__ __forceinline__ short8 cvt8(const float* p){
  short8 v;
  #pragma unroll
  for (int e=0;e<8;e++) v[e] = (short)f2bf(p[e]);
  return v;
}
__device__ __forceinline__ unsigned int cvtpk_bf16(float a, float b){
  unsigned int r;  // dst.lo = bf16(a), dst.hi = bf16(b), RNE
  asm("v_cvt_pk_bf16_f32 %0, %1, %2" : "=v"(r) : "v"(a), "v"(b));
  return r;
}
__device__ __forceinline__ float fast_rcp(float x){         // v_rcp_f32
  float r; asm("v_rcp_f32 %0, %1" : "=v"(r) : "v"(x)); return r;
}
// raw LDS-only barrier: no vmcnt(0) drain
__device__ __forceinline__ void barrier_lds(){
  asm volatile("s_waitcnt lgkmcnt(0)\n\ts_barrier" ::: "memory");
}

// ---------------- xproj: xp[t][b][j] = inp[b][t][:]@wi[:,j] + brec[j] (bf16) --------
__global__ __launch_bounds__(256,2) void xproj_kernel(
    const float* __restrict__ inp, const float* __restrict__ wi,
    const float* __restrict__ brec, unsigned short* __restrict__ xp)
{
  const int t = blockIdx.x, tid = threadIdx.x;
  const int wv = tid>>6, lane = tid&63, col = lane&15, quad = lane>>4;
  __shared__ __align__(16) unsigned short inA[64*80];   // [b][i], pad 80
  {
    int r = tid>>2, i0 = (tid&3)*16;
    const float* src = inp + ((size_t)r*Tn + t)*In_ + i0;
    unsigned short tmp[16];
    #pragma unroll
    for (int q=0;q<16;q++) tmp[q] = f2bf(src[q]);
    *(short8*)&inA[r*80 + i0]     = *(short8*)&tmp[0];
    *(short8*)&inA[r*80 + i0 + 8] = *(short8*)&tmp[8];
  }
  const int wnb = wv*128;
  short8 bw[8][2];
  float brecv[8];
  #pragma unroll
  for (int nt=0;nt<8;nt++){
    int j = wnb + nt*16 + col;
    brecv[nt] = brec[j];
    #pragma unroll
    for (int ks=0;ks<2;ks++){
      float tmp[8];
      #pragma unroll
      for (int e=0;e<8;e++) tmp[e] = wi[(size_t)(ks*32 + quad*8 + e)*Hn + j];
      bw[nt][ks] = cvt8(tmp);
    }
  }
  __syncthreads();
  floatx4 acc[4][8];
  #pragma unroll
  for (int mt=0;mt<4;mt++)
    #pragma unroll
    for (int nt=0;nt<8;nt++) acc[mt][nt] = (floatx4){0.f,0.f,0.f,0.f};
  #pragma unroll
  for (int ks=0;ks<2;ks++)
    #pragma unroll
    for (int mt=0;mt<4;mt++){
      short8 ar = *(const short8*)&inA[(mt*16+col)*80 + ks*32 + quad*8];
      #pragma unroll
      for (int nt=0;nt<8;nt++)
        acc[mt][nt] = __builtin_amdgcn_mfma_f32_16x16x32_bf16(ar, bw[nt][ks], acc[mt][nt],0,0,0);
    }
  #pragma unroll
  for (int mt=0;mt<4;mt++)
    #pragma unroll
    for (int nt=0;nt<8;nt++)
      #pragma unroll
      for (int r=0;r<4;r++){
        int b = mt*16 + quad*4 + r;
        int j = wnb + nt*16 + col;
        xp[((size_t)t*Bn + b)*Hn + j] = f2bf(acc[mt][nt][r] + brecv[nt]);
      }
}

// ------------- wrec_pack: bf16 A-frags, layout [ks][jt] (512KB) + flags reset -------
__global__ __launch_bounds__(256,1) void wrec_pack(
    const float* __restrict__ wrec, unsigned short* __restrict__ wrecB,
    unsigned int* flags)
{
  if (blockIdx.x==0 && threadIdx.x<2) flags[threadIdx.x] = 0u;
  int gl = blockIdx.x*256 + threadIdx.x;      // 0..32767
  int fi = gl>>6, lane = gl&63;
  int ks = fi>>5, jt = fi&31;
  int j = jt*16 + (lane&15);
  int k = ks*32 + (lane>>4)*8;
  short8 v = cvt8(wrec + (size_t)j*Hn + k);
  *(short8*)(wrecB + (size_t)gl*8) = v;
}

// ------------- scan: 8 blocks x 512 threads; j-split + flag-synced exchange ---------
// Block p: bh=p&1 (b in [32bh,32bh+32)), jq=p>>1 (j in [128jq,128jq+128)).
// Wave wv owns j-range 16 (jt = jq*8+wv), b=32 (2 b-tiles).  Per wave: 32 MFMA;
// per SIMD (2 waves): 64 MFMA ~ 1240cy — 4x less matrix-pipe time than the 4-CU
// version (r7-r10 were matrix-pipe-bound at 256 MFMA/SIMD/step).
// ALL of wrec for the wave is register-resident: awr[16] = 128 regs. No A-LDS,
// no A-streaming.  h exchange per step: epilogue nt-stores h(t) slice to hs[t]
// (needed anyway), threadfence, atomicAdd flags[bh]; consumers spin to 4t,
// acquire, stage 3 peer j-quarters (24KB, L3-hot) -> hA.  Own quarter written
// to hA directly by epilogue.  hs slots are fresh addresses each step -> no
// stale-cache hazard; flags are device-scope atomics.  hA dbuf 64KB LDS.
__global__ __launch_bounds__(512,2) void rnn_scan(
    const float* __restrict__ h0,
    const unsigned short* xp,            // ws+64KB  [T][B][H] bf16 (aliases hs+1 slot)
    const unsigned short* __restrict__ wrecB,
    unsigned short* hs,                  // ws       [T][B][H] bf16
    unsigned int* flags)                 // [2], zeroed by wrec_pack
{
  const int tid  = threadIdx.x;
  const int p    = blockIdx.x;
  const int bh   = p & 1;               // batch half
  const int jq   = p >> 1;              // j quarter
  const int wv   = tid >> 6;            // 0..7
  const int lane = tid & 63;
  const int col  = lane & 15;
  const int quad = lane >> 4;
  const int jbase = jq*128 + wv*16;     // wave's 16 j's

  __shared__ __align__(16) unsigned short hA[2*16384];   // 64KB: 2 x 32 frags x 512

  // A-frags: ALL 16 k-slices register-resident (jt = jq*8+wv)
  short8 awr[16];
  {
    const int jt = jq*8 + wv;
    #pragma unroll
    for (int ks=0;ks<16;ks++)
      awr[ks] = *(const short8*)(wrecB + ((size_t)(ks*32 + jt)*64 + lane)*8);
  }

  // h0 -> hA buffer 0; frag layout: (b,k) at ((k>>5)*2+(b>>4))*512 + (((k>>3)&3)*16+(b&15))*8 + (k&7)
  for (int idx = tid; idx < 32*Hn; idx += 512){
    int b = idx >> 9, k = idx & 511;
    hA[(((k>>5)*2 + (b>>4))*512 + (((k>>3)&3)*16 + (b&15))*8 + (k&7))] = f2bf(h0[k]);
  }
  // fp32 h master: lane owns (b = bh*32+bt*16+col, j = jbase+quad*4+r); h0 indep of b
  float hm[2][4];
  #pragma unroll
  for (int bt=0;bt<2;bt++)
    #pragma unroll
    for (int r=0;r<4;r++) hm[bt][r] = h0[jbase + quad*4 + r];

  // loop-invariant offsets
  int xoff[2], woff[2];
  #pragma unroll
  for (int bt=0;bt<2;bt++){
    xoff[bt] = (bh*32 + bt*16 + col)*Hn + jbase + quad*4;
    int j0q = jbase + quad*4;
    woff[bt] = ((j0q>>5)*2 + bt)*512 + (((j0q>>3)&3)*16 + col)*8 + (quad&1)*4;
  }
  const unsigned short* xq = xp;        // uniform, bumped per step (SGPR)
  unsigned short* hq = hs;
  int hoff = 0;

  floatx4 p00={0,0,0,0}, p01={0,0,0,0}, p10={0,0,0,0}, p11={0,0,0,0};

  __syncthreads();

  for (int t = 0; t < Tn; t++){
    if (t > 0){
      // wait for all 4 same-bh blocks to have published h(t) (= end of step t-1)
      if (tid == 0){
        unsigned target = 4u*(unsigned)t;
        while (__hip_atomic_load(flags + bh, __ATOMIC_ACQUIRE, __HIP_MEMORY_SCOPE_AGENT) < target)
          __builtin_amdgcn_s_sleep(1);
      }
      __syncthreads();
      __threadfence();
      // stage 3 peer j-quarters from hs[t-1] -> hA(cur)
      {
        int b = tid >> 4, jr = (tid & 15)*8;
        const unsigned short* hr = hq - (Bn*Hn) + (size_t)(bh*32 + b)*Hn + jr;
        int q0 = ((jq+1)&3)*128, q1 = ((jq+2)&3)*128, q2 = ((jq+3)&3)*128;
        short8 v0 = *(const short8*)(hr + q0);
        short8 v1 = *(const short8*)(hr + q1);
        short8 v2 = *(const short8*)(hr + q2);
        int jo0 = jr + q0, jo1 = jr + q1, jo2 = jr + q2;
        int inb = (b>>4)*512 + (b&15)*8;
        *(short8*)&hA[hoff + (jo0>>5)*1024 + inb + ((jo0>>3)&3)*128] = v0;
        *(short8*)&hA[hoff + (jo1>>5)*1024 + inb + ((jo1>>3)&3)*128] = v1;
        *(short8*)&hA[hoff + (jo2>>5)*1024 + inb + ((jo2>>3)&3)*128] = v2;
      }
    }
    barrier_lds();   // staging + prev epilogue's own-slice writes visible CU-wide

    // xproj for this step (consumed in epilogue; drains under the sweep)
    u64 xv0 = *(const u64*)(xq + xoff[0]);
    u64 xv1 = *(const u64*)(xq + xoff[1]);

    // ---- sweep: 16 ks x 2 b-tiles, A in regs, 4 accumulation chains ----
    const unsigned short* hcb = hA + hoff + lane*8;
    #pragma unroll
    for (int ks=0;ks<16;ks++){
      short8 hb0 = *(const short8*)(hcb + (2*ks  )*512);
      short8 hb1 = *(const short8*)(hcb + (2*ks+1)*512);
      if ((ks&1)==0){
        p00 = __builtin_amdgcn_mfma_f32_16x16x32_bf16(awr[ks], hb0, p00,0,0,0);
        p10 = __builtin_amdgcn_mfma_f32_16x16x32_bf16(awr[ks], hb1, p10,0,0,0);
      } else {
        p01 = __builtin_amdgcn_mfma_f32_16x16x32_bf16(awr[ks], hb0, p01,0,0,0);
        p11 = __builtin_amdgcn_mfma_f32_16x16x32_bf16(awr[ks], hb1, p11,0,0,0);
      }
    }

    // ---- epilogue: 8 values/lane; write hA(next) own-slice + hs[t] ----
    unsigned short* hw = hA + (hoff ^ 16384);
    #pragma unroll
    for (int bt=0;bt<2;bt++){
      floatx4 s;
      if (bt==0){ s.x=p00.x+p01.x; s.y=p00.y+p01.y; s.z=p00.z+p01.z; s.w=p00.w+p01.w; }
      else      { s.x=p10.x+p11.x; s.y=p10.y+p11.y; s.z=p10.z+p11.z; s.w=p10.w+p11.w; }
      u64 x = (bt==0) ? xv0 : xv1;
      float hn[4];
      #pragma unroll
      for (int r=0;r<4;r++){
        float pre = s[r] + bf2f((unsigned short)(x >> (16*r)));
        float e   = __expf(2.0f*pre);
        float rc  = fast_rcp(e + 1.0f);
        float v   = __builtin_fmaf(0.5f, hm[bt][r], 0.5f) - rc;
        hm[bt][r] = v;
        hn[r] = v;
      }
      unsigned int lo = cvtpk_bf16(hn[0], hn[1]);
      unsigned int hi = cvtpk_bf16(hn[2], hn[3]);
      uint2 w; w.x = lo; w.y = hi;
      *(uint2*)&hw[woff[bt]] = w;                      // hA(next), frag layout (8B)
      u64 pk = (u64)lo | ((u64)hi << 32);
      __builtin_nontemporal_store(pk, (u64*)(hq + xoff[bt]));   // hs[t][b][j..j+3]
    }
    p00=(floatx4){0,0,0,0}; p01=(floatx4){0,0,0,0};
    p10=(floatx4){0,0,0,0}; p11=(floatx4){0,0,0,0};

    // publish: all threads' stores drained, then one flag bump
    __threadfence();
    __syncthreads();
    if (tid == 0)
      __hip_atomic_fetch_add(flags + bh, 1u, __ATOMIC_RELEASE, __HIP_MEMORY_SCOPE_AGENT);

    hoff ^= 16384;
    xq += Bn*Hn;
    hq += Bn*Hn;
  }
}

// ------------- out: out[b][t][o] = hs[t][b][:] @ wo ; rows m = t*64+b ---------------
__global__ __launch_bounds__(256,1) void out_gemm(
    const unsigned short* __restrict__ hs,
    const float* __restrict__ wo,
    float* __restrict__ out)
{
  const int tid = threadIdx.x, bid = blockIdx.x;
  const int wv = tid >> 6, lane = tid & 63, col = lane & 15, quad = lane >> 4;
  const int m0 = bid*64;
  __shared__ __align__(16) unsigned short hsA[64][520];

  for (int c = tid; c < 64*64; c += 256){
    int r = c >> 6, cc = (c & 63)*8;
    *(short8*)&hsA[r][cc] = *(const short8*)(hs + (size_t)(m0 + r)*Hn + cc);
  }
  short8 boh[16], bol[16];
  #pragma unroll
  for (int kk = 0; kk < 16; kk++){
    float tmp[8];
    #pragma unroll
    for (int e = 0; e < 8; e++) tmp[e] = wo[(size_t)(kk*32 + quad*8 + e)*On + wv*16 + col];
    #pragma unroll
    for (int e = 0; e < 8; e++){
      unsigned short h = f2bf(tmp[e]);
      boh[kk][e] = (short)h;
      bol[kk][e] = (short)f2bf(tmp[e] - bf2f(h));
    }
  }
  __syncthreads();

  floatx4 acc[4];
  #pragma unroll
  for (int ms=0;ms<4;ms++) acc[ms] = (floatx4){0.f,0.f,0.f,0.f};
  #pragma unroll
  for (int kk = 0; kk < 16; kk++){
    int k = kk*32 + quad*8;
    #pragma unroll
    for (int ms = 0; ms < 4; ms++){
      short8 a = *(const short8*)&hsA[ms*16 + col][k];
      acc[ms] = __builtin_amdgcn_mfma_f32_16x16x32_bf16(a, boh[kk], acc[ms], 0,0,0);
      acc[ms] = __builtin_amdgcn_mfma_f32_16x16x32_bf16(a, bol[kk], acc[ms], 0,0,0);
    }
  }
  #pragma unroll
  for (int ms = 0; ms < 4; ms++)
    #pragma unroll
    for (int r = 0; r < 4; r++){
      int m = m0 + ms*16 + quad*4 + r;     // m = t*64 + b
      int b = m & 63, tt = m >> 6;
      out[((size_t)b*Tn + tt)*On + wv*16 + col] = acc[ms][r];
    }
}

extern "C" void kernel_launch(void* const* d_in, const int* in_sizes, int n_in,
                              void* d_out, int out_size, void* d_ws, size_t ws_size,
                              hipStream_t stream){
  const float* inp  = (const float*)d_in[0];
  const float* wi   = (const float*)d_in[1];
  const float* wrec = (const float*)d_in[2];
  const float* wo   = (const float*)d_in[3];
  const float* brec = (const float*)d_in[4];
  const float* h0   = (const float*)d_in[5];
  float* out = (float*)d_out;

  char* ws = (char*)d_ws;
  // hs slots: ws + t*64KB. xp slots: ws + 64KB + t*64KB (= hs slot t+1).
  // Scan step t writes hs[t] (destroys xp[t-1], already consumed; same-bh blocks
  // are flag-locked within one step, cross-bh rows disjoint -> alias safe).
  // wrecB (512KB packed frags, [ks][jt]) past the last xp slot; flags after it.
  unsigned short* hs = (unsigned short*)ws;
  unsigned short* xp = (unsigned short*)(ws + 65536);
  unsigned short* wrecB = (unsigned short*)(ws + (size_t)Tn*Bn*Hn*2 + 65536);
  unsigned int* flags = (unsigned int*)(ws + (size_t)Tn*Bn*Hn*2 + 65536 + 524288);

  xproj_kernel<<<Tn, 256, 0, stream>>>(inp, wi, brec, xp);
  wrec_pack  <<<128, 256, 0, stream>>>(wrec, wrecB, flags);
  rnn_scan   <<<8, 512, 0, stream>>>(h0, xp, wrecB, hs, flags);
  out_gemm   <<<(Bn*Tn)/64, 256, 0, stream>>>(hs, wo, out);
}

// Round 12
// 4392.021 us; speedup vs baseline: 1.7293x; 1.7293x over previous
//
#include <hip/hip_runtime.h>

#define Tn 1024
#define Bn 64
#define In_ 64
#define Hn 512
#define On 64
#define DTC 0.5f

typedef __attribute__((ext_vector_type(8))) short short8;   // bf16x8 MFMA frag
typedef __attribute__((ext_vector_type(4))) float floatx4;  // MFMA C frag
typedef unsigned long long u64;

__device__ __forceinline__ float bf2f(unsigned short u){
  union{unsigned int i; float f;} v; v.i = ((unsigned int)u)<<16; return v.f;
}
__device__ __forceinline__ unsigned short f2bf(float f){   // RNE
  union{float f; unsigned int i;} v; v.f=f;
  unsigned int x=v.i;
  return (unsigned short)((x + 0x7fffu + ((x>>16)&1u))>>16);
}
__device__ __forceinline__ short8 cvt8(const float* p){
  short8 v;
  #pragma unroll
  for (int e=0;e<8;e++) v[e] = (short)f2bf(p[e]);
  return v;
}
__device__ __forceinline__ unsigned int cvtpk_bf16(float a, float b){
  unsigned int r;  // dst.lo = bf16(a), dst.hi = bf16(b), RNE
  asm("v_cvt_pk_bf16_f32 %0, %1, %2" : "=v"(r) : "v"(a), "v"(b));
  return r;
}
__device__ __forceinline__ float fast_rcp(float x){         // v_rcp_f32
  float r; asm("v_rcp_f32 %0, %1" : "=v"(r) : "v"(x)); return r;
}
// raw LDS-only barrier: no vmcnt(0) drain — global loads/stores keep flying
// across it (this is what makes cross-step VMEM prefetch legal and useful).
__device__ __forceinline__ void barrier_lds(){
  asm volatile("s_waitcnt lgkmcnt(0)\n\ts_barrier" ::: "memory");
}

// ---------------- xproj: xp[t][b][j] = inp[b][t][:]@wi[:,j] + brec[j] (bf16) --------
__global__ __launch_bounds__(256,2) void xproj_kernel(
    const float* __restrict__ inp, const float* __restrict__ wi,
    const float* __restrict__ brec, unsigned short* __restrict__ xp)
{
  const int t = blockIdx.x, tid = threadIdx.x;
  const int wv = tid>>6, lane = tid&63, col = lane&15, quad = lane>>4;
  __shared__ __align__(16) unsigned short inA[64*80];   // [b][i], pad 80
  {
    int r = tid>>2, i0 = (tid&3)*16;
    const float* src = inp + ((size_t)r*Tn + t)*In_ + i0;
    unsigned short tmp[16];
    #pragma unroll
    for (int q=0;q<16;q++) tmp[q] = f2bf(src[q]);
    *(short8*)&inA[r*80 + i0]     = *(short8*)&tmp[0];
    *(short8*)&inA[r*80 + i0 + 8] = *(short8*)&tmp[8];
  }
  const int wnb = wv*128;
  short8 bw[8][2];
  float brecv[8];
  #pragma unroll
  for (int nt=0;nt<8;nt++){
    int j = wnb + nt*16 + col;
    brecv[nt] = brec[j];
    #pragma unroll
    for (int ks=0;ks<2;ks++){
      float tmp[8];
      #pragma unroll
      for (int e=0;e<8;e++) tmp[e] = wi[(size_t)(ks*32 + quad*8 + e)*Hn + j];
      bw[nt][ks] = cvt8(tmp);
    }
  }
  __syncthreads();
  floatx4 acc[4][8];
  #pragma unroll
  for (int mt=0;mt<4;mt++)
    #pragma unroll
    for (int nt=0;nt<8;nt++) acc[mt][nt] = (floatx4){0.f,0.f,0.f,0.f};
  #pragma unroll
  for (int ks=0;ks<2;ks++)
    #pragma unroll
    for (int mt=0;mt<4;mt++){
      short8 ar = *(const short8*)&inA[(mt*16+col)*80 + ks*32 + quad*8];
      #pragma unroll
      for (int nt=0;nt<8;nt++)
        acc[mt][nt] = __builtin_amdgcn_mfma_f32_16x16x32_bf16(ar, bw[nt][ks], acc[mt][nt],0,0,0);
    }
  #pragma unroll
  for (int mt=0;mt<4;mt++)
    #pragma unroll
    for (int nt=0;nt<8;nt++)
      #pragma unroll
      for (int r=0;r<4;r++){
        int b = mt*16 + quad*4 + r;
        int j = wnb + nt*16 + col;
        xp[((size_t)t*Bn + b)*Hn + j] = f2bf(acc[mt][nt][r] + brecv[nt]);
      }
}

// ------------- wrec_pack: bf16 A-frags, layout [ks][jt] (512KB) ---------------------
// frag fi = ks*32+jt (ks=k-slice 0..15, jt=j-tile 0..31); lane l holds
// wrec[jt*16 + (l&15)][ks*32 + (l>>4)*8 + e], e=0..7  -> wrecB[(fi*64+l)*8 + e]
__global__ __launch_bounds__(256,1) void wrec_pack(
    const float* __restrict__ wrec, unsigned short* __restrict__ wrecB)
{
  int gl = blockIdx.x*256 + threadIdx.x;      // 0..32767
  int fi = gl>>6, lane = gl&63;
  int ks = fi>>5, jt = fi&31;
  int j = jt*16 + (lane&15);
  int k = ks*32 + (lane>>4)*8;
  short8 v = cvt8(wrec + (size_t)j*Hn + k);
  *(short8*)(wrecB + (size_t)gl*8) = v;
}

// ------------- scan: 4 blocks x 512 threads (8 waves = 2/SIMD) ----------------------
// pre^T[j][b] = sum_k wrec[j][k] h[b][k].  Wave wv owns j in [64wv,64wv+64) (mt=0..3).
// r11's cross-CU split reverted (L3-bound exchange).  This = r7 (best, 2740us)
// with the A-operand shifted further onto the PROVEN-hideable VMEM pipe:
//   ks 0..5  -> reg (accum 96 + acc 16 = 112)
//   ks 6,7   -> LDS wrecL (32KB persistent)     -> LDS reads 256->192/CU/step
//   ks 8..15 -> streamed L2 via the SAME 4-buffer structure as r7 (each buffer
//               reloads twice/step; in-flight footprint identical).  s8..s11
//               carry cross-step leads (~6400cy); s12..s15 get 6-block (~470cy)
//               leads vs ~300cy L2 latency.  L2 port 256KB/step/CU ~ 4000cy,
//               under the step.  r9's failure was a 5th buffer — not repeated.
// hA dbuf 32KB, one LDS-only barrier/step.  No sched_barrier/setprio.
__global__ __launch_bounds__(512,2) void rnn_scan(
    const float* __restrict__ h0,
    const unsigned short* xp,            // ws+64KB  [T][B][H] bf16 (aliases hs+1 slot)
    const unsigned short* __restrict__ wrecB,
    unsigned short* hs)                  // ws       [T][B][H] bf16
{
  const int tid  = threadIdx.x;
  const int g    = blockIdx.x;          // batch group: b in [16g, 16g+16)
  const int wv   = tid >> 6;            // 0..7
  const int lane = tid & 63;
  const int col  = lane & 15;
  const int quad = lane >> 4;
  const int wbase = wv*64;

  __shared__ __align__(16) unsigned short wrecL[2*32*512]; // 32KB: slices 6,7
  __shared__ __align__(16) unsigned short hA[2*8192];      // 32KB: h frags, dbuf

  // frag (ks, jt=wv*4+mt) lives at wrecB[((ks*32 + wv*4 + mt)*64 + lane)*8]
  const unsigned short* pw = wrecB + ((size_t)(wv*4)*64 + lane)*8;
  #define WOFF(ks,mt) ((size_t)((ks)*32 + (mt))*512)

  // A-frags ks 0..5, register-resident (accum side)
  short8 awr[4][6];
  #pragma unroll
  for (int mt=0;mt<4;mt++)
    #pragma unroll
    for (int ks=0;ks<6;ks++)
      awr[mt][ks] = *(const short8*)(pw + WOFF(ks,mt));

  // A-frags ks 6,7 -> LDS; frag (jt=wv*4+mt, s) at ((wv*4+mt)*2+s)*512 shorts
  #pragma unroll
  for (int s=0;s<2;s++)
    #pragma unroll
    for (int mt=0;mt<4;mt++)
      *(short8*)&wrecL[((wv*4+mt)*2+s)*512 + lane*8] =
          *(const short8*)(pw + WOFF(6+s,mt));
  const unsigned short* wl = wrecL + (wv*8)*512 + lane*8;  // + (mt*2+s)*512 imm

  // h0 -> hA buffer 0 (frag layout: (b,k) at ((k>>5)*64+((k>>3)&3)*16+b)*8+(k&7))
  for (int idx = tid; idx < 16*Hn; idx += 512){
    int b = idx >> 9, k = idx & 511;
    hA[(((k>>5)*64 + ((k>>3)&3)*16 + b))*8 + (k&7)] = f2bf(h0[k]);
  }
  // fp32 h master: lane owns (b=col, j = wbase+mt*16+quad*4+r)
  float hm[4][4];
  #pragma unroll
  for (int mt=0;mt<4;mt++)
    #pragma unroll
    for (int r=0;r<4;r++) hm[mt][r] = h0[wbase + mt*16 + quad*4 + r];

  floatx4 acc[4];
  #pragma unroll
  for (int mt=0;mt<4;mt++) acc[mt] = (floatx4){0.f,0.f,0.f,0.f};

  // loop-invariant offsets
  const int row = g*16 + col;           // global batch for this lane
  int xoff[4], woff[4];
  #pragma unroll
  for (int mt=0;mt<4;mt++){
    int j4 = wbase + mt*16 + quad*4;
    xoff[mt] = row*Hn + j4;
    woff[mt] = (((j4>>5)*64 + ((j4>>3)&3)*16 + col))*8 + (j4&7);
  }
  const unsigned short* xq = xp;        // uniform, bumped per step (SGPR)
  unsigned short* hq = hs;
  int hoff = 0;

  __syncthreads();

  #define MFMA4R(KS, HB) { \
    _Pragma("unroll") \
    for (int mt=0;mt<4;mt++) \
      acc[mt] = __builtin_amdgcn_mfma_f32_16x16x32_bf16(awr[mt][KS], (HB), acc[mt],0,0,0); }
  #define MFMA4W(W, HB) { \
    _Pragma("unroll") \
    for (int mt=0;mt<4;mt++) \
      acc[mt] = __builtin_amdgcn_mfma_f32_16x16x32_bf16((W)[mt], (HB), acc[mt],0,0,0); }
  #define MFMA4L(S, HB) { \
    _Pragma("unroll") \
    for (int mt=0;mt<4;mt++){ \
      short8 aw = *(const short8*)(wl + (mt*2+(S))*512); \
      acc[mt] = __builtin_amdgcn_mfma_f32_16x16x32_bf16(aw, (HB), acc[mt],0,0,0); } }
  #define LOADW(W, KS) { \
    _Pragma("unroll") \
    for (int mt=0;mt<4;mt++) (W)[mt] = *(const short8*)(pw + WOFF(KS,mt)); }
  #define RDHB(S) (*(const short8*)(hc + (S)*512))

  // cross-step prefetch of streamed slices 8..11 (wrec is step-invariant)
  short8 wstA[4], wstB[4], wstC[4], wstD[4];
  LOADW(wstA, 8); LOADW(wstB, 9); LOADW(wstC, 10); LOADW(wstD, 11);

  for (int t = 0; t < Tn; t++){
    // step-top: xproj loads (consumed in epilogue; drain under the sweep)
    u64 xv[4];
    #pragma unroll
    for (int mt=0;mt<4;mt++) xv[mt] = *(const u64*)(xq + xoff[mt]);

    const unsigned short* hc = hA + hoff + lane*8;

    // B0..B5: reg slices 0..5
    #pragma unroll
    for (int ks=0;ks<6;ks++){
      short8 hb = RDHB(ks);
      MFMA4R(ks, hb);
    }
    { short8 hb = RDHB(8);  MFMA4W(wstA, hb); }  LOADW(wstA, 12);  // B6:  ks8  (x-step)
    { short8 hb = RDHB(9);  MFMA4W(wstB, hb); }  LOADW(wstB, 13);  // B7:  ks9  (x-step)
    { short8 hb = RDHB(10); MFMA4W(wstC, hb); }  LOADW(wstC, 14);  // B8:  ks10 (x-step)
    { short8 hb = RDHB(11); MFMA4W(wstD, hb); }  LOADW(wstD, 15);  // B9:  ks11 (x-step)
    { short8 hb = RDHB(6);  MFMA4L(0, hb); }                       // B10: ks6 (LDS)
    { short8 hb = RDHB(7);  MFMA4L(1, hb); }                       // B11: ks7 (LDS)
    { short8 hb = RDHB(12); MFMA4W(wstA, hb); }  LOADW(wstA, 8);   // B12: ks12 -> t+1
    { short8 hb = RDHB(13); MFMA4W(wstB, hb); }  LOADW(wstB, 9);   // B13: ks13 -> t+1
    { short8 hb = RDHB(14); MFMA4W(wstC, hb); }  LOADW(wstC, 10);  // B14: ks14 -> t+1
    { short8 hb = RDHB(15); MFMA4W(wstD, hb); }  LOADW(wstD, 11);  // B15: ks15 -> t+1

    // epilogue: writes go to the OTHER hA buffer -> no pre-barrier needed.
    // tanh(pre) = 1 - 2/(e^{2pre}+1); hn = fma(.5,hm,.5) - rcp(e+1)
    unsigned short* hw = hA + (hoff ^ 8192);
    #pragma unroll
    for (int mt=0;mt<4;mt++){
      u64 x = xv[mt];
      float hn[4];
      #pragma unroll
      for (int r=0;r<4;r++){
        float pre = acc[mt][r] + bf2f((unsigned short)(x >> (16*r)));
        float e   = __expf(2.0f*pre);                  // v_mul + v_exp
        float rc  = fast_rcp(e + 1.0f);                // v_add + v_rcp
        float v   = __builtin_fmaf(0.5f, hm[mt][r], 0.5f) - rc;
        hm[mt][r] = v;
        hn[r] = v;
      }
      unsigned int lo = cvtpk_bf16(hn[0], hn[1]);
      unsigned int hi = cvtpk_bf16(hn[2], hn[3]);
      uint2 w; w.x = lo; w.y = hi;
      *(uint2*)&hw[woff[mt]] = w;                      // ds_write_b64, frag layout
      u64 pk = (u64)lo | ((u64)hi << 32);
      __builtin_nontemporal_store(pk, (u64*)(hq + xoff[mt]));   // hs[t][b][j4..j4+3]
      acc[mt] = (floatx4){0.f,0.f,0.f,0.f};
    }
    barrier_lds();     // LDS ops drained CU-wide; prefetched VMEM keeps flying
    hoff ^= 8192;
    xq += Bn*Hn;
    hq += Bn*Hn;
  }
  #undef MFMA4R
  #undef MFMA4W
  #undef MFMA4L
  #undef LOADW
  #undef RDHB
  #undef WOFF
}

// ------------- out: out[b][t][o] = hs[t][b][:] @ wo ; rows m = t*64+b ---------------
__global__ __launch_bounds__(256,1) void out_gemm(
    const unsigned short* __restrict__ hs,
    const float* __restrict__ wo,
    float* __restrict__ out)
{
  const int tid = threadIdx.x, bid = blockIdx.x;
  const int wv = tid >> 6, lane = tid & 63, col = lane & 15, quad = lane >> 4;
  const int m0 = bid*64;
  __shared__ __align__(16) unsigned short hsA[64][520];

  for (int c = tid; c < 64*64; c += 256){
    int r = c >> 6, cc = (c & 63)*8;
    *(short8*)&hsA[r][cc] = *(const short8*)(hs + (size_t)(m0 + r)*Hn + cc);
  }
  short8 boh[16], bol[16];
  #pragma unroll
  for (int kk = 0; kk < 16; kk++){
    float tmp[8];
    #pragma unroll
    for (int e = 0; e < 8; e++) tmp[e] = wo[(size_t)(kk*32 + quad*8 + e)*On + wv*16 + col];
    #pragma unroll
    for (int e = 0; e < 8; e++){
      unsigned short h = f2bf(tmp[e]);
      boh[kk][e] = (short)h;
      bol[kk][e] = (short)f2bf(tmp[e] - bf2f(h));
    }
  }
  __syncthreads();

  floatx4 acc[4];
  #pragma unroll
  for (int ms=0;ms<4;ms++) acc[ms] = (floatx4){0.f,0.f,0.f,0.f};
  #pragma unroll
  for (int kk = 0; kk < 16; kk++){
    int k = kk*32 + quad*8;
    #pragma unroll
    for (int ms = 0; ms < 4; ms++){
      short8 a = *(const short8*)&hsA[ms*16 + col][k];
      acc[ms] = __builtin_amdgcn_mfma_f32_16x16x32_bf16(a, boh[kk], acc[ms], 0,0,0);
      acc[ms] = __builtin_amdgcn_mfma_f32_16x16x32_bf16(a, bol[kk], acc[ms], 0,0,0);
    }
  }
  #pragma unroll
  for (int ms = 0; ms < 4; ms++)
    #pragma unroll
    for (int r = 0; r < 4; r++){
      int m = m0 + ms*16 + quad*4 + r;     // m = t*64 + b
      int b = m & 63, tt = m >> 6;
      out[((size_t)b*Tn + tt)*On + wv*16 + col] = acc[ms][r];
    }
}

extern "C" void kernel_launch(void* const* d_in, const int* in_sizes, int n_in,
                              void* d_out, int out_size, void* d_ws, size_t ws_size,
                              hipStream_t stream){
  const float* inp  = (const float*)d_in[0];
  const float* wi   = (const float*)d_in[1];
  const float* wrec = (const float*)d_in[2];
  const float* wo   = (const float*)d_in[3];
  const float* brec = (const float*)d_in[4];
  const float* h0   = (const float*)d_in[5];
  float* out = (float*)d_out;

  char* ws = (char*)d_ws;
  // hs slots: ws + t*64KB. xp slots: ws + 64KB + t*64KB (= hs slot t+1).
  // Scan step t writes hs[t] (destroys xp[t-1], already consumed; per-group
  // b-slices disjoint, so cross-block skew is safe). wrecB (512KB packed
  // bf16 frags, [ks][jt] order) lives past the last xp slot.
  unsigned short* hs = (unsigned short*)ws;
  unsigned short* xp = (unsigned short*)(ws + 65536);
  unsigned short* wrecB = (unsigned short*)(ws + (size_t)Tn*Bn*Hn*2 + 65536);

  xproj_kernel<<<Tn, 256, 0, stream>>>(inp, wi, brec, xp);
  wrec_pack  <<<128, 256, 0, stream>>>(wrec, wrecB);
  rnn_scan   <<<4, 512, 0, stream>>>(h0, xp, wrecB, hs);
  out_gemm   <<<(Bn*Tn)/64, 256, 0, stream>>>(hs, wo, out);
}

// Round 13
// 2855.385 us; speedup vs baseline: 2.6599x; 1.5382x over previous
//
#include <hip/hip_runtime.h>

#define Tn 1024
#define Bn 64
#define In_ 64
#define Hn 512
#define On 64
#define DTC 0.5f

typedef __attribute__((ext_vector_type(8))) short short8;   // bf16x8 MFMA frag
typedef __attribute__((ext_vector_type(4))) float floatx4;  // MFMA C frag
typedef unsigned long long u64;

__device__ __forceinline__ float bf2f(unsigned short u){
  union{unsigned int i; float f;} v; v.i = ((unsigned int)u)<<16; return v.f;
}
__device__ __forceinline__ unsigned short f2bf(float f){   // RNE
  union{float f; unsigned int i;} v; v.f=f;
  unsigned int x=v.i;
  return (unsigned short)((x + 0x7fffu + ((x>>16)&1u))>>16);
}
__device__ __forceinline__ short8 cvt8(const float* p){
  short8 v;
  #pragma unroll
  for (int e=0;e<8;e++) v[e] = (short)f2bf(p[e]);
  return v;
}
__device__ __forceinline__ unsigned int cvtpk_bf16(float a, float b){
  unsigned int r;  // dst.lo = bf16(a), dst.hi = bf16(b), RNE
  asm("v_cvt_pk_bf16_f32 %0, %1, %2" : "=v"(r) : "v"(a), "v"(b));
  return r;
}
__device__ __forceinline__ float fast_rcp(float x){         // v_rcp_f32
  float r; asm("v_rcp_f32 %0, %1" : "=v"(r) : "v"(x)); return r;
}
// raw LDS-only barrier: no vmcnt(0) drain — global loads/stores keep flying
// across it (this is what makes cross-step VMEM prefetch legal and useful).
__device__ __forceinline__ void barrier_lds(){
  asm volatile("s_waitcnt lgkmcnt(0)\n\ts_barrier" ::: "memory");
}

// ---------------- xproj: xp[t][b][j] = inp[b][t][:]@wi[:,j] + brec[j] (bf16) --------
__global__ __launch_bounds__(256,2) void xproj_kernel(
    const float* __restrict__ inp, const float* __restrict__ wi,
    const float* __restrict__ brec, unsigned short* __restrict__ xp)
{
  const int t = blockIdx.x, tid = threadIdx.x;
  const int wv = tid>>6, lane = tid&63, col = lane&15, quad = lane>>4;
  __shared__ __align__(16) unsigned short inA[64*80];   // [b][i], pad 80
  {
    int r = tid>>2, i0 = (tid&3)*16;
    const float* src = inp + ((size_t)r*Tn + t)*In_ + i0;
    unsigned short tmp[16];
    #pragma unroll
    for (int q=0;q<16;q++) tmp[q] = f2bf(src[q]);
    *(short8*)&inA[r*80 + i0]     = *(short8*)&tmp[0];
    *(short8*)&inA[r*80 + i0 + 8] = *(short8*)&tmp[8];
  }
  const int wnb = wv*128;
  short8 bw[8][2];
  float brecv[8];
  #pragma unroll
  for (int nt=0;nt<8;nt++){
    int j = wnb + nt*16 + col;
    brecv[nt] = brec[j];
    #pragma unroll
    for (int ks=0;ks<2;ks++){
      float tmp[8];
      #pragma unroll
      for (int e=0;e<8;e++) tmp[e] = wi[(size_t)(ks*32 + quad*8 + e)*Hn + j];
      bw[nt][ks] = cvt8(tmp);
    }
  }
  __syncthreads();
  floatx4 acc[4][8];
  #pragma unroll
  for (int mt=0;mt<4;mt++)
    #pragma unroll
    for (int nt=0;nt<8;nt++) acc[mt][nt] = (floatx4){0.f,0.f,0.f,0.f};
  #pragma unroll
  for (int ks=0;ks<2;ks++)
    #pragma unroll
    for (int mt=0;mt<4;mt++){
      short8 ar = *(const short8*)&inA[(mt*16+col)*80 + ks*32 + quad*8];
      #pragma unroll
      for (int nt=0;nt<8;nt++)
        acc[mt][nt] = __builtin_amdgcn_mfma_f32_16x16x32_bf16(ar, bw[nt][ks], acc[mt][nt],0,0,0);
    }
  #pragma unroll
  for (int mt=0;mt<4;mt++)
    #pragma unroll
    for (int nt=0;nt<8;nt++)
      #pragma unroll
      for (int r=0;r<4;r++){
        int b = mt*16 + quad*4 + r;
        int j = wnb + nt*16 + col;
        xp[((size_t)t*Bn + b)*Hn + j] = f2bf(acc[mt][nt][r] + brecv[nt]);
      }
}

// ------------- wrec_pack: bf16 A-frags, layout [ks][jt] (512KB) ---------------------
// frag fi = ks*32+jt (ks=k-slice 0..15, jt=j-tile 0..31); lane l holds
// wrec[jt*16 + (l&15)][ks*32 + (l>>4)*8 + e], e=0..7  -> wrecB[(fi*64+l)*8 + e]
__global__ __launch_bounds__(256,1) void wrec_pack(
    const float* __restrict__ wrec, unsigned short* __restrict__ wrecB)
{
  int gl = blockIdx.x*256 + threadIdx.x;      // 0..32767
  int fi = gl>>6, lane = gl&63;
  int ks = fi>>5, jt = fi&31;
  int j = jt*16 + (lane&15);
  int k = ks*32 + (lane>>4)*8;
  short8 v = cvt8(wrec + (size_t)j*Hn + k);
  *(short8*)(wrecB + (size_t)gl*8) = v;
}

// ------------- scan: 4 blocks x 512 threads (8 waves = 2/SIMD) ----------------------
// pre^T[j][b] = sum_k wrec[j][k] h[b][k].  Wave wv owns j in [64wv,64wv+64) (mt=0..3).
// BEST CONFIG (r7/r10, 2740us scan, reproduced 2x).  Constrained optimum:
//  - regs: 256/wave saturated (awr 96 + acc 16 accum; staging 64 + rest arch)
//  - LDS: 160KB saturated (wrecL 128KB + hA dbuf 32KB)
//  - L2 stream budget: 6 slices = 192KB/step/CU ~ the hideable max (7->+30%,
//    8->+56% measured regressions; r9/r12)
// wrec is STEP-INVARIANT + barrier_lds doesn't drain vmcnt -> streamed slices
// reloaded right after consumption FOR THE NEXT STEP (VMEM off critical path).
// Slice plan: ks0..5 reg | ks6..9 LDS (128KB) | ks10..15 streamed
// (10,11 cross-step persistent; 12..15 via two rotating bufs).  hA dbuf 32KB,
// one LDS-only barrier/step.  No sched_barrier/setprio: compiler schedules.
__global__ __launch_bounds__(512,2) void rnn_scan(
    const float* __restrict__ h0,
    const unsigned short* xp,            // ws+64KB  [T][B][H] bf16 (aliases hs+1 slot)
    const unsigned short* __restrict__ wrecB,
    unsigned short* hs)                  // ws       [T][B][H] bf16
{
  const int tid  = threadIdx.x;
  const int g    = blockIdx.x;          // batch group: b in [16g, 16g+16)
  const int wv   = tid >> 6;            // 0..7
  const int lane = tid & 63;
  const int col  = lane & 15;
  const int quad = lane >> 4;
  const int wbase = wv*64;

  __shared__ __align__(16) unsigned short wrecL[4*32*512]; // 128KB: slices 6..9
  __shared__ __align__(16) unsigned short hA[2*8192];      // 32KB: h frags, dbuf

  // frag (ks, jt=wv*4+mt) lives at wrecB[((ks*32 + wv*4 + mt)*64 + lane)*8]
  const unsigned short* pw = wrecB + ((size_t)(wv*4)*64 + lane)*8;
  #define WOFF(ks,mt) ((size_t)((ks)*32 + (mt))*512)

  // A-frags ks 0..5, register-resident (accum side)
  short8 awr[4][6];
  #pragma unroll
  for (int mt=0;mt<4;mt++)
    #pragma unroll
    for (int ks=0;ks<6;ks++)
      awr[mt][ks] = *(const short8*)(pw + WOFF(ks,mt));

  // A-frags ks 6..9 -> LDS; frag (jt=wv*4+mt, s) at ((wv*4+mt)*4+s)*512 shorts
  #pragma unroll
  for (int s=0;s<4;s++)
    #pragma unroll
    for (int mt=0;mt<4;mt++)
      *(short8*)&wrecL[((wv*4+mt)*4+s)*512 + lane*8] =
          *(const short8*)(pw + WOFF(6+s,mt));
  const unsigned short* wl = wrecL + (wv*16)*512 + lane*8;  // + (mt*4+s)*512 imm

  // h0 -> hA buffer 0 (frag layout: (b,k) at ((k>>5)*64+((k>>3)&3)*16+b)*8+(k&7))
  for (int idx = tid; idx < 16*Hn; idx += 512){
    int b = idx >> 9, k = idx & 511;
    hA[(((k>>5)*64 + ((k>>3)&3)*16 + b))*8 + (k&7)] = f2bf(h0[k]);
  }
  // fp32 h master: lane owns (b=col, j = wbase+mt*16+quad*4+r)
  float hm[4][4];
  #pragma unroll
  for (int mt=0;mt<4;mt++)
    #pragma unroll
    for (int r=0;r<4;r++) hm[mt][r] = h0[wbase + mt*16 + quad*4 + r];

  floatx4 acc[4];
  #pragma unroll
  for (int mt=0;mt<4;mt++) acc[mt] = (floatx4){0.f,0.f,0.f,0.f};

  // loop-invariant offsets
  const int row = g*16 + col;           // global batch for this lane
  int xoff[4], woff[4];
  #pragma unroll
  for (int mt=0;mt<4;mt++){
    int j4 = wbase + mt*16 + quad*4;
    xoff[mt] = row*Hn + j4;
    woff[mt] = (((j4>>5)*64 + ((j4>>3)&3)*16 + col))*8 + (j4&7);
  }
  const unsigned short* xq = xp;        // uniform, bumped per step (SGPR)
  unsigned short* hq = hs;
  int hoff = 0;

  __syncthreads();

  #define MFMA4R(KS, HB) { \
    _Pragma("unroll") \
    for (int mt=0;mt<4;mt++) \
      acc[mt] = __builtin_amdgcn_mfma_f32_16x16x32_bf16(awr[mt][KS], (HB), acc[mt],0,0,0); }
  #define MFMA4W(W, HB) { \
    _Pragma("unroll") \
    for (int mt=0;mt<4;mt++) \
      acc[mt] = __builtin_amdgcn_mfma_f32_16x16x32_bf16((W)[mt], (HB), acc[mt],0,0,0); }
  #define MFMA4L(S, HB) { \
    _Pragma("unroll") \
    for (int mt=0;mt<4;mt++){ \
      short8 aw = *(const short8*)(wl + (mt*4+(S))*512); \
      acc[mt] = __builtin_amdgcn_mfma_f32_16x16x32_bf16(aw, (HB), acc[mt],0,0,0); } }
  #define LOADW(W, KS) { \
    _Pragma("unroll") \
    for (int mt=0;mt<4;mt++) (W)[mt] = *(const short8*)(pw + WOFF(KS,mt)); }
  #define RDHB(S) (*(const short8*)(hc + (S)*512))

  // cross-step prefetch of streamed slices 10,11 (wrec is step-invariant)
  short8 wstP0[4], wstP1[4], wstA[4], wstB[4];
  LOADW(wstP0, 10); LOADW(wstP1, 11);

  for (int t = 0; t < Tn; t++){
    // step-top: xproj loads (consumed in epilogue) + mid-sweep streams 12,13
    u64 xv[4];
    #pragma unroll
    for (int mt=0;mt<4;mt++) xv[mt] = *(const u64*)(xq + xoff[mt]);
    LOADW(wstA, 12); LOADW(wstB, 13);

    const unsigned short* hc = hA + hoff + lane*8;

    // ---- K-sweep in 2-slice superblocks: 2 hb reads -> 8 MFMAs ----
    { short8 h0_ = RDHB(0),  h1_ = RDHB(1);                          // P0: ks0,1 (reg)
      MFMA4R(0, h0_); MFMA4R(1, h1_); }
    { short8 h0_ = RDHB(2),  h1_ = RDHB(3);                          // P1: ks2,3 (reg)
      MFMA4R(2, h0_); MFMA4R(3, h1_); }
    { short8 h0_ = RDHB(4),  h1_ = RDHB(5);                          // P2: ks4,5 (reg)
      MFMA4R(4, h0_); MFMA4R(5, h1_); }
    { short8 h0_ = RDHB(12), h1_ = RDHB(13);                         // P3: ks12,13 (str)
      MFMA4W(wstA, h0_); MFMA4W(wstB, h1_); }
    LOADW(wstA, 14); LOADW(wstB, 15);                                //   -> ks14,15
    { short8 h0_ = RDHB(10), h1_ = RDHB(11);                         // P4: ks10,11 (str)
      MFMA4W(wstP0, h0_); MFMA4W(wstP1, h1_); }
    LOADW(wstP0, 10); LOADW(wstP1, 11);                              //   -> t+1
    { short8 h0_ = RDHB(6),  h1_ = RDHB(7);                          // P5: ks6,7 (LDS)
      MFMA4L(0, h0_); MFMA4L(1, h1_); }
    { short8 h0_ = RDHB(14), h1_ = RDHB(15);                         // P6: ks14,15 (str)
      MFMA4W(wstA, h0_); MFMA4W(wstB, h1_); }
    { short8 h0_ = RDHB(8),  h1_ = RDHB(9);                          // P7: ks8,9 (LDS)
      MFMA4L(2, h0_); MFMA4L(3, h1_); }

    // epilogue: writes go to the OTHER hA buffer -> no pre-barrier needed.
    // tanh(pre) = 1 - 2/(e^{2pre}+1); hn = fma(.5,hm,.5) - rcp(e+1)
    unsigned short* hw = hA + (hoff ^ 8192);
    #pragma unroll
    for (int mt=0;mt<4;mt++){
      u64 x = xv[mt];
      float hn[4];
      #pragma unroll
      for (int r=0;r<4;r++){
        float pre = acc[mt][r] + bf2f((unsigned short)(x >> (16*r)));
        float e   = __expf(2.0f*pre);                  // v_mul + v_exp
        float rc  = fast_rcp(e + 1.0f);                // v_add + v_rcp
        float v   = __builtin_fmaf(0.5f, hm[mt][r], 0.5f) - rc;
        hm[mt][r] = v;
        hn[r] = v;
      }
      unsigned int lo = cvtpk_bf16(hn[0], hn[1]);
      unsigned int hi = cvtpk_bf16(hn[2], hn[3]);
      uint2 w; w.x = lo; w.y = hi;
      *(uint2*)&hw[woff[mt]] = w;                      // ds_write_b64, frag layout
      u64 pk = (u64)lo | ((u64)hi << 32);
      __builtin_nontemporal_store(pk, (u64*)(hq + xoff[mt]));   // hs[t][b][j4..j4+3]
      acc[mt] = (floatx4){0.f,0.f,0.f,0.f};
    }
    barrier_lds();     // LDS ops drained CU-wide; prefetched VMEM keeps flying
    hoff ^= 8192;
    xq += Bn*Hn;
    hq += Bn*Hn;
  }
  #undef MFMA4R
  #undef MFMA4W
  #undef MFMA4L
  #undef LOADW
  #undef RDHB
  #undef WOFF
}

// ------------- out: out[b][t][o] = hs[t][b][:] @ wo ; rows m = t*64+b ---------------
__global__ __launch_bounds__(256,1) void out_gemm(
    const unsigned short* __restrict__ hs,
    const float* __restrict__ wo,
    float* __restrict__ out)
{
  const int tid = threadIdx.x, bid = blockIdx.x;
  const int wv = tid >> 6, lane = tid & 63, col = lane & 15, quad = lane >> 4;
  const int m0 = bid*64;
  __shared__ __align__(16) unsigned short hsA[64][520];

  for (int c = tid; c < 64*64; c += 256){
    int r = c >> 6, cc = (c & 63)*8;
    *(short8*)&hsA[r][cc] = *(const short8*)(hs + (size_t)(m0 + r)*Hn + cc);
  }
  short8 boh[16], bol[16];
  #pragma unroll
  for (int kk = 0; kk < 16; kk++){
    float tmp[8];
    #pragma unroll
    for (int e = 0; e < 8; e++) tmp[e] = wo[(size_t)(kk*32 + quad*8 + e)*On + wv*16 + col];
    #pragma unroll
    for (int e = 0; e < 8; e++){
      unsigned short h = f2bf(tmp[e]);
      boh[kk][e] = (short)h;
      bol[kk][e] = (short)f2bf(tmp[e] - bf2f(h));
    }
  }
  __syncthreads();

  floatx4 acc[4];
  #pragma unroll
  for (int ms=0;ms<4;ms++) acc[ms] = (floatx4){0.f,0.f,0.f,0.f};
  #pragma unroll
  for (int kk = 0; kk < 16; kk++){
    int k = kk*32 + quad*8;
    #pragma unroll
    for (int ms = 0; ms < 4; ms++){
      short8 a = *(const short8*)&hsA[ms*16 + col][k];
      acc[ms] = __builtin_amdgcn_mfma_f32_16x16x32_bf16(a, boh[kk], acc[ms], 0,0,0);
      acc[ms] = __builtin_amdgcn_mfma_f32_16x16x32_bf16(a, bol[kk], acc[ms], 0,0,0);
    }
  }
  #pragma unroll
  for (int ms = 0; ms < 4; ms++)
    #pragma unroll
    for (int r = 0; r < 4; r++){
      int m = m0 + ms*16 + quad*4 + r;     // m = t*64 + b
      int b = m & 63, tt = m >> 6;
      out[((size_t)b*Tn + tt)*On + wv*16 + col] = acc[ms][r];
    }
}

extern "C" void kernel_launch(void* const* d_in, const int* in_sizes, int n_in,
                              void* d_out, int out_size, void* d_ws, size_t ws_size,
                              hipStream_t stream){
  const float* inp  = (const float*)d_in[0];
  const float* wi   = (const float*)d_in[1];
  const float* wrec = (const float*)d_in[2];
  const float* wo   = (const float*)d_in[3];
  const float* brec = (const float*)d_in[4];
  const float* h0   = (const float*)d_in[5];
  float* out = (float*)d_out;

  char* ws = (char*)d_ws;
  // hs slots: ws + t*64KB. xp slots: ws + 64KB + t*64KB (= hs slot t+1).
  // Scan step t writes hs[t] (destroys xp[t-1], already consumed; per-group
  // b-slices disjoint, so cross-block skew is safe). wrecB (512KB packed
  // bf16 frags, [ks][jt] order) lives past the last xp slot.
  unsigned short* hs = (unsigned short*)ws;
  unsigned short* xp = (unsigned short*)(ws + 65536);
  unsigned short* wrecB = (unsigned short*)(ws + (size_t)Tn*Bn*Hn*2 + 65536);

  xproj_kernel<<<Tn, 256, 0, stream>>>(inp, wi, brec, xp);
  wrec_pack  <<<128, 256, 0, stream>>>(wrec, wrecB);
  rnn_scan   <<<4, 512, 0, stream>>>(h0, xp, wrecB, hs);
  out_gemm   <<<(Bn*Tn)/64, 256, 0, stream>>>(hs, wo, out);
}